// Round 1
// baseline (10123.370 us; speedup 1.0000x reference)
//
#include <hip/hip_runtime.h>
#include <math.h>

static constexpr int BATCH = 8;
static constexpr int NFC   = 128;   // NF
static constexpr int IMGS  = 64;    // IMG
static constexpr int PIX   = IMGS * IMGS;      // 4096
static constexpr int FIN   = NFC * 3;          // 384
static constexpr int FH    = NFC;              // 128
static constexpr int FO    = NFC * 2;          // 256
static constexpr int LATD  = 256;
static constexpr int KTOT  = 197376;
static constexpr int NCALLS = 16;

// kall offsets
static constexpr int OFF_WIN  = 0;
static constexpr int OFF_BIN  = 49152;
static constexpr int OFF_WMID = 49280;
static constexpr int OFF_BMID = 65664;
static constexpr int OFF_WOUT = 65792;
static constexpr int OFF_BOUT = 98560;
static constexpr int OFF_WSH  = 98816;
static constexpr int OFF_BSH  = 197120;

// -------------------- hypernetwork: kall = lat @ hyper_w + hyper_b --------------------
__global__ void hyper_kernel(const float* __restrict__ lat, const float* __restrict__ hw,
                             const float* __restrict__ hb, float* __restrict__ kall) {
    __shared__ float lat_s[BATCH * LATD];
    int tid = threadIdx.x;
    for (int i = tid; i < BATCH * LATD; i += 256) lat_s[i] = lat[i];
    __syncthreads();
    int j = blockIdx.x * 256 + tid;
    float acc[BATCH];
#pragma unroll
    for (int b = 0; b < BATCH; b++) acc[b] = 0.f;
#pragma unroll 4
    for (int k = 0; k < LATD; k++) {
        float w = hw[(size_t)k * KTOT + j];
#pragma unroll
        for (int b = 0; b < BATCH; b++) acc[b] += lat_s[b * LATD + k] * w;
    }
    float bias = hb[j];
#pragma unroll
    for (int b = 0; b < BATCH; b++) kall[(size_t)b * KTOT + j] = acc[b] + bias;
}

// -------------------- float4 copy --------------------
__global__ void copy4_kernel(const float4* __restrict__ src, float4* __restrict__ dst, int n4) {
    int i = blockIdx.x * 256 + threadIdx.x;
    if (i < n4) dst[i] = src[i];
}

// -------------------- per-step: sobel dwconv + per-channel norm, writes p (384 ch) ------
__global__ void norm_kernel(const float* __restrict__ state, float* __restrict__ p) {
    __shared__ float buf[PIX];      // 16 KB
    __shared__ float rbuf[12];
    int c = blockIdx.x, b = blockIdx.y;
    const float* src = state + ((size_t)b * NFC + c) * PIX;
    int tid = threadIdx.x;
    for (int i = tid; i < PIX; i += 256) buf[i] = src[i];
    __syncthreads();

    const float S0 = 6.123233995736766e-17f, S1 = 0.70710678118654752f, S2 = 1.0f;
    const float Sv[5] = {S0, S1, S2, S1, S0};
    const float Dv[5] = {-1.0f, -0.70710678118654752f, 0.0f, 0.70710678118654752f, 1.0f};

    float px[16], py[16], v0[16];
#pragma unroll
    for (int i = 0; i < 16; i++) {
        int pix = tid + 256 * i;
        int y = pix >> 6, x = pix & 63;
        float ax = 0.f, ay = 0.f;
#pragma unroll
        for (int t = 0; t < 25; t++) {
            int dy = t / 5 - 2, dx = t % 5 - 2;
            int yy = y + dy, xx = x + dx;
            bool ok = (yy >= 0) && (yy < IMGS) && (xx >= 0) && (xx < IMGS);
            float v = ok ? buf[yy * IMGS + xx] : 0.f;
            ax += Sv[dy + 2] * Dv[dx + 2] * v;
            ay += Dv[dy + 2] * Sv[dx + 2] * v;
        }
        px[i] = ax; py[i] = ay; v0[i] = buf[pix];
    }

    int lane = tid & 63, wv = tid >> 6;
    // pass 1: sums -> means
    float s0 = 0.f, s1 = 0.f, s2 = 0.f;
#pragma unroll
    for (int i = 0; i < 16; i++) { s0 += v0[i]; s1 += px[i]; s2 += py[i]; }
    for (int off = 32; off > 0; off >>= 1) {
        s0 += __shfl_down(s0, off); s1 += __shfl_down(s1, off); s2 += __shfl_down(s2, off);
    }
    if (lane == 0) { rbuf[wv] = s0; rbuf[4 + wv] = s1; rbuf[8 + wv] = s2; }
    __syncthreads();
    float mu0 = (rbuf[0] + rbuf[1] + rbuf[2] + rbuf[3]) * (1.f / PIX);
    float mu1 = (rbuf[4] + rbuf[5] + rbuf[6] + rbuf[7]) * (1.f / PIX);
    float mu2 = (rbuf[8] + rbuf[9] + rbuf[10] + rbuf[11]) * (1.f / PIX);
    __syncthreads();
    // pass 2: variance (two-pass avoids cancellation at |x|~450)
    float q0 = 0.f, q1 = 0.f, q2 = 0.f;
#pragma unroll
    for (int i = 0; i < 16; i++) {
        float d0 = v0[i] - mu0, d1 = px[i] - mu1, d2 = py[i] - mu2;
        q0 += d0 * d0; q1 += d1 * d1; q2 += d2 * d2;
    }
    for (int off = 32; off > 0; off >>= 1) {
        q0 += __shfl_down(q0, off); q1 += __shfl_down(q1, off); q2 += __shfl_down(q2, off);
    }
    if (lane == 0) { rbuf[wv] = q0; rbuf[4 + wv] = q1; rbuf[8 + wv] = q2; }
    __syncthreads();
    float var0 = (rbuf[0] + rbuf[1] + rbuf[2] + rbuf[3]) * (1.f / PIX);
    float var1 = (rbuf[4] + rbuf[5] + rbuf[6] + rbuf[7]) * (1.f / PIX);
    float var2 = (rbuf[8] + rbuf[9] + rbuf[10] + rbuf[11]) * (1.f / PIX);
    float sc0 = rsqrtf(var0 + 1e-5f), sc1 = rsqrtf(var1 + 1e-5f), sc2 = rsqrtf(var2 + 1e-5f);

    float* p0 = p + ((size_t)b * FIN + c) * PIX;
    float* p1 = p + ((size_t)b * FIN + 128 + c) * PIX;
    float* p2 = p + ((size_t)b * FIN + 256 + c) * PIX;
#pragma unroll
    for (int i = 0; i < 16; i++) {
        int pix = tid + 256 * i;
        p0[pix] = (v0[i] - mu0) * sc0;
        p1[pix] = (px[i] - mu1) * sc1;
        p2[pix] = (py[i] - mu2) * sc2;
    }
}

// -------------------- fp32 tiled GEMM: C[M][4096] = act(scale*W @ X + bias) -----------
// W = kall + b*KTOT + woff (row-major [M][K]); bias = kall + b*KTOT + boff
__global__ void gemm_kernel(const float* __restrict__ kall, int woff, int boff,
                            const float* __restrict__ X, float* __restrict__ C,
                            int M, int K, float scale, int act, int accum) {
    __shared__ float Ws[16][68];   // padded: 16B-aligned rows, low conflict
    __shared__ float Xs[16][64];
    int b = blockIdx.z;
    const float* W    = kall + (size_t)b * KTOT + woff;
    const float* bias = kall + (size_t)b * KTOT + boff;
    const float* Xb   = X + (size_t)b * K * PIX;
    float* Cb         = C + (size_t)b * M * PIX;
    int bn = blockIdx.x * 64, bm = blockIdx.y * 64;
    int tid = threadIdx.x, tx = tid & 15, ty = tid >> 4;
    float acc[4][4];
#pragma unroll
    for (int i = 0; i < 4; i++)
#pragma unroll
        for (int j = 0; j < 4; j++) acc[i][j] = 0.f;

    for (int k0 = 0; k0 < K; k0 += 16) {
#pragma unroll
        for (int u = 0; u < 4; u++) {
            int idx = tid + 256 * u;
            int m = idx >> 4, kk = idx & 15;
            Ws[kk][m] = W[(size_t)(bm + m) * K + k0 + kk] * scale;
        }
#pragma unroll
        for (int u = 0; u < 4; u++) {
            int idx = tid + 256 * u;
            int n = idx & 63, kk = idx >> 6;
            Xs[kk][n] = Xb[(size_t)(k0 + kk) * PIX + bn + n];
        }
        __syncthreads();
#pragma unroll
        for (int kk = 0; kk < 16; kk++) {
            float4 av = *(const float4*)&Ws[kk][ty * 4];
            float4 bv = *(const float4*)&Xs[kk][tx * 4];
            acc[0][0] += av.x * bv.x; acc[0][1] += av.x * bv.y; acc[0][2] += av.x * bv.z; acc[0][3] += av.x * bv.w;
            acc[1][0] += av.y * bv.x; acc[1][1] += av.y * bv.y; acc[1][2] += av.y * bv.z; acc[1][3] += av.y * bv.w;
            acc[2][0] += av.z * bv.x; acc[2][1] += av.z * bv.y; acc[2][2] += av.z * bv.z; acc[2][3] += av.z * bv.w;
            acc[3][0] += av.w * bv.x; acc[3][1] += av.w * bv.y; acc[3][2] += av.w * bv.z; acc[3][3] += av.w * bv.w;
        }
        __syncthreads();
    }
#pragma unroll
    for (int i = 0; i < 4; i++) {
        int m = bm + ty * 4 + i;
        float bv = bias[m];
        float4 v = make_float4(acc[i][0] + bv, acc[i][1] + bv, acc[i][2] + bv, acc[i][3] + bv);
        float4* cp = (float4*)&Cb[(size_t)m * PIX + bn + tx * 4];
        if (accum) {
            float4 o = *cp;
            v.x += o.x; v.y += o.y; v.z += o.z; v.w += o.w;
        }
        if (act) {
            v.x = fmaxf(v.x, 0.f); v.y = fmaxf(v.y, 0.f);
            v.z = fmaxf(v.z, 0.f); v.w = fmaxf(v.w, 0.f);
        }
        *cp = v;
    }
}

// -------------------- gating + leaky update --------------------
__global__ void gate_kernel(const float* __restrict__ dn, const float* __restrict__ oldS,
                            float* __restrict__ newS, const float* __restrict__ leak_p) {
    float leak = fminf(fmaxf(leak_p[0], 0.001f), 1000.f);
    int i = blockIdx.x * 256 + threadIdx.x;   // over B*NF*PIX = 4194304
    int b = i >> 19;                          // / (NF*PIX)
    int r = i & (NFC * PIX - 1);
    float val  = dn[(size_t)b * FO * PIX + r];
    float gate = dn[(size_t)b * FO * PIX + NFC * PIX + r];
    float sg = 1.f / (1.f + expf(-gate));
    newS[i] = oldS[i] + leak * val * sg;
}

// -------------------- 3x3 conv, 128->128, optional relu / residual --------------------
__global__ void conv3x3_kernel(const float* __restrict__ in, const float* __restrict__ W,
                               const float* __restrict__ bias, const float* __restrict__ resid,
                               float* __restrict__ outp, int relu) {
    __shared__ float in_s[16][6][64];   // 24 KB
    int b = blockIdx.z, ocg = blockIdx.y, yt = blockIdx.x;
    int y0 = yt * 4;
    int tid = threadIdx.x;
    int ry = tid >> 6, x = tid & 63;
    int y = y0 + ry;
    float acc[16];
#pragma unroll
    for (int o = 0; o < 16; o++) acc[o] = bias[ocg * 16 + o];

    for (int cc = 0; cc < 8; cc++) {
        __syncthreads();
        for (int idx = tid; idx < 16 * 6 * 64; idx += 256) {
            int ch = idx / 384; int rr = (idx / 64) % 6; int xx = idx & 63;
            int yy = y0 - 1 + rr;
            float v = 0.f;
            if (yy >= 0 && yy < IMGS) v = in[(((size_t)b * NFC + cc * 16 + ch) * IMGS + yy) * IMGS + xx];
            in_s[ch][rr][xx] = v;
        }
        __syncthreads();
        const float* Wb = W + ((size_t)(ocg * 16) * NFC + cc * 16) * 9;  // advance o by NFC*9
#pragma unroll
        for (int c = 0; c < 16; c++) {
#pragma unroll
            for (int tap = 0; tap < 9; tap++) {
                int dy = tap / 3 - 1, dx = tap % 3 - 1;
                int xx = x + dx;
                float v = (xx >= 0 && xx < IMGS) ? in_s[c][ry + 1 + dy][xx] : 0.f;
#pragma unroll
                for (int o = 0; o < 16; o++)
                    acc[o] += Wb[((size_t)o * NFC + c) * 9 + tap] * v;   // wave-uniform -> s_load
            }
        }
    }
#pragma unroll
    for (int o = 0; o < 16; o++) {
        float v = acc[o];
        size_t off = (((size_t)b * NFC + ocg * 16 + o) * IMGS + y) * IMGS + x;
        if (resid) v += resid[off];
        if (relu) v = fmaxf(v, 0.f);
        outp[off] = v;
    }
}

// -------------------- final 3-channel image conv + clip --------------------
__global__ void img_kernel(const float* __restrict__ y, const float* __restrict__ W,
                           const float* __restrict__ bias, float* __restrict__ oimg,
                           float* __restrict__ oraw) {
    int b = blockIdx.y;
    int pix = blockIdx.x * 256 + threadIdx.x;
    int yy0 = pix >> 6, xx0 = pix & 63;
    float acc[3] = {bias[0], bias[1], bias[2]};
    for (int c = 0; c < NFC; c++) {
        const float* yp = y + ((size_t)b * NFC + c) * PIX;
#pragma unroll
        for (int tap = 0; tap < 9; tap++) {
            int dy = tap / 3 - 1, dx = tap % 3 - 1;
            int yy = yy0 + dy, xx = xx0 + dx;
            float v = (yy >= 0 && yy < IMGS && xx >= 0 && xx < IMGS) ? yp[yy * IMGS + xx] : 0.f;
#pragma unroll
            for (int o = 0; o < 3; o++) acc[o] += W[((size_t)o * NFC + c) * 9 + tap] * v;
        }
    }
#pragma unroll
    for (int o = 0; o < 3; o++) {
        size_t off = ((size_t)b * 3 + o) * PIX + pix;
        oraw[off] = acc[o];
        oimg[off] = fminf(fmaxf(acc[o], -1.f), 1.f);
    }
}

extern "C" void kernel_launch(void* const* d_in, const int* in_sizes, int n_in,
                              void* d_out, int out_size, void* d_ws, size_t ws_size,
                              hipStream_t stream) {
    const float* lat     = (const float*)d_in[0];
    const float* ca_init = (const float*)d_in[1];
    const float* leak    = (const float*)d_in[2];
    const float* hyper_w = (const float*)d_in[3];
    const float* hyper_b = (const float*)d_in[4];
    const float* res_w1  = (const float*)d_in[5];
    const float* res_b1  = (const float*)d_in[6];
    const float* res_w2  = (const float*)d_in[7];
    const float* res_b2  = (const float*)d_in[8];
    const float* img_w   = (const float*)d_in[9];
    const float* img_b   = (const float*)d_in[10];

    float* out      = (float*)d_out;
    float* out_img  = out;
    float* embs     = out + (size_t)BATCH * 3 * PIX;                  // 98304
    float* out_raw  = embs + (size_t)(NCALLS + 1) * BATCH * NFC * PIX;

    float* ws   = (float*)d_ws;
    float* kall = ws;
    float* p    = kall + (size_t)BATCH * KTOT;        // 1,579,008
    float* h1   = p  + (size_t)BATCH * FIN * PIX;     // +12,582,912
    float* h2   = h1 + (size_t)BATCH * NFC * PIX;     // +4,194,304
    float* dn   = h2 + (size_t)BATCH * NFC * PIX;     // +4,194,304 (dn: 8,388,608)
    float* hres = h1;   // reused after the step loop
    float* ybuf = h2;

    const float rsq384 = 0.051031036307982884f;  // 1/sqrt(384)
    const float rsq128 = 0.088388347648318447f;  // 1/sqrt(128)

    hyper_kernel<<<KTOT / 256, 256, 0, stream>>>(lat, hyper_w, hyper_b, kall);

    int n4 = BATCH * NFC * PIX / 4;
    copy4_kernel<<<(n4 + 255) / 256, 256, 0, stream>>>((const float4*)ca_init, (float4*)embs, n4);

    const size_t stateN = (size_t)BATCH * NFC * PIX;
    for (int t = 0; t < NCALLS; t++) {
        const float* cur = embs + (size_t)t * stateN;
        float* nxt = embs + (size_t)(t + 1) * stateN;
        norm_kernel<<<dim3(NFC, BATCH), 256, 0, stream>>>(cur, p);
        gemm_kernel<<<dim3(64, FH / 64, BATCH), 256, 0, stream>>>(kall, OFF_WIN,  OFF_BIN,  p,  h1, FH, FIN, rsq384, 1, 0);
        gemm_kernel<<<dim3(64, FH / 64, BATCH), 256, 0, stream>>>(kall, OFF_WMID, OFF_BMID, h1, h2, FH, FH,  rsq128, 1, 0);
        gemm_kernel<<<dim3(64, FO / 64, BATCH), 256, 0, stream>>>(kall, OFF_WOUT, OFF_BOUT, h2, dn, FO, FH,  rsq128, 0, 0);
        gemm_kernel<<<dim3(64, FO / 64, BATCH), 256, 0, stream>>>(kall, OFF_WSH,  OFF_BSH,  p,  dn, FO, FIN, rsq384, 0, 1);
        gate_kernel<<<(int)(stateN / 256), 256, 0, stream>>>(dn, cur, nxt, leak);
    }

    const float* fin = embs + (size_t)NCALLS * stateN;
    conv3x3_kernel<<<dim3(16, 8, BATCH), 256, 0, stream>>>(fin,  res_w1, res_b1, nullptr, hres, 1);
    conv3x3_kernel<<<dim3(16, 8, BATCH), 256, 0, stream>>>(hres, res_w2, res_b2, fin,     ybuf, 0);
    img_kernel<<<dim3(16, BATCH), 256, 0, stream>>>(ybuf, img_w, img_b, out_img, out_raw);
}